// Round 1
// baseline (39.488 us; speedup 1.0000x reference)
//
#include <hip/hip_runtime.h>

// Problem constants (from the reference module)
constexpr int BH = 16 * 768;      // B*C*H total rows
constexpr int H  = 768;
constexpr int W  = 1280;
constexpr int W4 = W / 4;         // float4 per row
constexpr int PAD = 4;            // KERNEL_SIZE/2 — equals float4 width!
constexpr int NVEC = BH * W4;     // total float4 elements

__global__ __launch_bounds__(256)
void bilateral_kernel(const float4* __restrict__ img,
                      const float4* __restrict__ disp,
                      float4* __restrict__ out)
{
    int idx = blockIdx.x * blockDim.x + threadIdx.x;
    if (idx >= NVEC) return;

    const int c4  = idx % W4;     // vector column
    const int row = idx / W4;     // global row (b*H + r, C==1)
    const int r   = row % H;      // row within image

    const float DIST = __expf(-16.0f / 9.0f);   // exp(-(pad²+pad²)/(2·3²)), const-folded
    const float EPS  = 1e-12f;

    // center image vector
    float4 a = img[idx];

    // img[r+4][c+4 .. c+7] — shift by 4 == one float4, aligned; zero outside
    float4 s = make_float4(0.f, 0.f, 0.f, 0.f);
    if (r + PAD < H && c4 + 1 < W4)
        s = img[idx + PAD * W4 + 1];

    // estDisp[r-4][c-4 .. c-1] — zero outside
    float4 d = make_float4(0.f, 0.f, 0.f, 0.f);
    if (r >= PAD && c4 >= 1)
        d = disp[idx - PAD * W4 - 1];

    float av[4] = {a.x, a.y, a.z, a.w};
    float sv[4] = {s.x, s.y, s.z, s.w};
    float dv[4] = {d.x, d.y, d.z, d.w};
    float ov[4];

#pragma unroll
    for (int k = 0; k < 4; ++k) {
        float diff = av[k] - sv[k];
        float w = DIST * __expf(diff * diff * -0.125f);  // exp(-diff²/(2·2²))
        ov[k] = (dv[k] * w + EPS) / (w + EPS);
    }

    out[idx] = make_float4(ov[0], ov[1], ov[2], ov[3]);
}

extern "C" void kernel_launch(void* const* d_in, const int* in_sizes, int n_in,
                              void* d_out, int out_size, void* d_ws, size_t ws_size,
                              hipStream_t stream) {
    const float4* img  = (const float4*)d_in[0];   // leftImage
    const float4* disp = (const float4*)d_in[1];   // estDisp
    float4* out = (float4*)d_out;

    const int block = 256;
    const int grid  = (NVEC + block - 1) / block;  // 15360 blocks
    bilateral_kernel<<<grid, block, 0, stream>>>(img, disp, out);
}